// Round 1
// baseline (2226.706 us; speedup 1.0000x reference)
//
#include <hip/hip_runtime.h>
#include <math.h>

// Problem constants
// B=256, T=512, E=768, Hd=50, 4*Hd=200, H=100, K=11, START=9, STOP=10, NEG=-1000

// ---------------------------------------------------------------------------
// Kernel 1: xw[M=131072][400] = emb[M][768] @ concat(W_ih_f, W_ih_b)^T
// BM=256, BN=64 (7 col blocks cover padded N=448), BK=16, 256 threads,
// 8x8 register tile per thread.
// ---------------------------------------------------------------------------
__global__ __launch_bounds__(256) void k_gemm_xw(
    const float* __restrict__ emb,
    const float* __restrict__ Wf,
    const float* __restrict__ Wb,
    float* __restrict__ xw)
{
    __shared__ float As[16][256];
    __shared__ float Bs[16][64];
    const int tid = threadIdx.x;
    const int m0 = blockIdx.x * 256;
    const int n0 = blockIdx.y * 64;

    const int lrow = tid >> 2;   // 0..63
    const int lkq  = tid & 3;    // 0..3  (float4 index along k)

    float4 apf[4];
    float4 bpf;

    // prefetch kt=0
    {
        #pragma unroll
        for (int p = 0; p < 4; ++p) {
            int row = lrow + p * 64;
            apf[p] = *(const float4*)(emb + (size_t)(m0 + row) * 768 + lkq * 4);
        }
        int n = n0 + lrow;
        if (n < 200)      bpf = *(const float4*)(Wf + (size_t)n * 768 + lkq * 4);
        else if (n < 400) bpf = *(const float4*)(Wb + (size_t)(n - 200) * 768 + lkq * 4);
        else              bpf = make_float4(0.f, 0.f, 0.f, 0.f);
    }

    float acc[8][8];
    #pragma unroll
    for (int i = 0; i < 8; ++i)
        #pragma unroll
        for (int j = 0; j < 8; ++j) acc[i][j] = 0.f;

    const int rg = tid >> 3;  // 0..31 (rows rg*8..+7)
    const int cg = tid & 7;   // 0..7  (cols cg*8..+7)

    for (int kt = 0; kt < 48; ++kt) {
        __syncthreads();
        #pragma unroll
        for (int p = 0; p < 4; ++p) {
            int row = lrow + p * 64;
            As[lkq * 4 + 0][row] = apf[p].x;
            As[lkq * 4 + 1][row] = apf[p].y;
            As[lkq * 4 + 2][row] = apf[p].z;
            As[lkq * 4 + 3][row] = apf[p].w;
        }
        Bs[lkq * 4 + 0][lrow] = bpf.x;
        Bs[lkq * 4 + 1][lrow] = bpf.y;
        Bs[lkq * 4 + 2][lrow] = bpf.z;
        Bs[lkq * 4 + 3][lrow] = bpf.w;
        __syncthreads();

        if (kt + 1 < 48) {
            const int k0 = (kt + 1) * 16;
            #pragma unroll
            for (int p = 0; p < 4; ++p) {
                int row = lrow + p * 64;
                apf[p] = *(const float4*)(emb + (size_t)(m0 + row) * 768 + k0 + lkq * 4);
            }
            int n = n0 + lrow;
            if (n < 200)      bpf = *(const float4*)(Wf + (size_t)n * 768 + k0 + lkq * 4);
            else if (n < 400) bpf = *(const float4*)(Wb + (size_t)(n - 200) * 768 + k0 + lkq * 4);
            else              bpf = make_float4(0.f, 0.f, 0.f, 0.f);
        }

        #pragma unroll
        for (int kk = 0; kk < 16; ++kk) {
            float4 a0 = *(const float4*)&As[kk][rg * 8];
            float4 a1 = *(const float4*)&As[kk][rg * 8 + 4];
            float4 b0 = *(const float4*)&Bs[kk][cg * 8];
            float4 b1 = *(const float4*)&Bs[kk][cg * 8 + 4];
            float av[8] = {a0.x, a0.y, a0.z, a0.w, a1.x, a1.y, a1.z, a1.w};
            float bv[8] = {b0.x, b0.y, b0.z, b0.w, b1.x, b1.y, b1.z, b1.w};
            #pragma unroll
            for (int i = 0; i < 8; ++i)
                #pragma unroll
                for (int j = 0; j < 8; ++j)
                    acc[i][j] = fmaf(av[i], bv[j], acc[i][j]);
        }
    }

    #pragma unroll
    for (int i = 0; i < 8; ++i) {
        int m = m0 + rg * 8 + i;
        #pragma unroll
        for (int j = 0; j < 8; ++j) {
            int n = n0 + cg * 8 + j;
            if (n < 400) xw[(size_t)m * 400 + n] = acc[i][j];
        }
    }
}

// ---------------------------------------------------------------------------
// Kernel 2: bidirectional LSTM recurrence. One block per (batch, dir).
// W_hh rows held in VGPRs (thread g owns gate g's 50 weights); h broadcast
// via uniform-address float4 LDS reads; gate exchange through LDS.
// Bias is added here (not in the GEMM). xw row for t+1 prefetched.
// ---------------------------------------------------------------------------
__global__ __launch_bounds__(256) void k_lstm(
    const float* __restrict__ xw,     // [131072][400] (fwd gates 0..199, bwd 200..399)
    const float* __restrict__ Whh_f,  // [200][50]
    const float* __restrict__ Whh_b,
    const float* __restrict__ bf_,    // [200]
    const float* __restrict__ bb_,
    float* __restrict__ hout)         // [131072][100] (fwd 0..49, bwd 50..99)
{
    const int b   = blockIdx.x >> 1;
    const int dir = blockIdx.x & 1;
    const int g   = threadIdx.x;

    __shared__ float h_s[52];
    __shared__ float g_s[200];

    const float* Whh  = dir ? Whh_b : Whh_f;
    const float* bias = dir ? bb_ : bf_;

    float w[52];
    float bg = 0.f;
    if (g < 200) {
        #pragma unroll
        for (int j = 0; j < 50; ++j) w[j] = Whh[g * 50 + j];
        w[50] = 0.f; w[51] = 0.f;
        bg = bias[g];
    } else {
        #pragma unroll
        for (int j = 0; j < 52; ++j) w[j] = 0.f;
    }

    if (g < 52) h_s[g] = 0.f;
    float c = 0.f;
    __syncthreads();

    const size_t base = (size_t)b * 512;

    float xv = 0.f;
    {
        int t0 = dir ? 511 : 0;
        if (g < 200) xv = xw[(base + t0) * 400 + dir * 200 + g];
    }

    for (int it = 0; it < 512; ++it) {
        const int t = dir ? (511 - it) : it;
        float xcur = xv;
        if (it + 1 < 512) {
            int tn = dir ? (510 - it) : (it + 1);
            if (g < 200) xv = xw[(base + tn) * 400 + dir * 200 + g];
        }

        float sum = bg + xcur;
        const float4* h4 = (const float4*)h_s;
        #pragma unroll
        for (int q = 0; q < 13; ++q) {
            float4 hv = h4[q];
            sum = fmaf(w[q * 4 + 0], hv.x, sum);
            sum = fmaf(w[q * 4 + 1], hv.y, sum);
            sum = fmaf(w[q * 4 + 2], hv.z, sum);
            sum = fmaf(w[q * 4 + 3], hv.w, sum);
        }
        if (g < 200) g_s[g] = sum;
        __syncthreads();

        if (g < 50) {
            float gi = g_s[g];
            float gf = g_s[g + 50];
            float gg = g_s[g + 100];
            float go = g_s[g + 150];
            float si = 1.f / (1.f + expf(-gi));
            float sf = 1.f / (1.f + expf(-gf));
            float so = 1.f / (1.f + expf(-go));
            c = sf * c + si * tanhf(gg);
            float h = so * tanhf(c);
            hout[(base + t) * 100 + dir * 50 + g] = h;
            h_s[g] = h;
        }
        __syncthreads();
    }
}

// ---------------------------------------------------------------------------
// Kernel 3: emissions logits[bt][11] = hout[bt][100] @ Wout^T + bout
// One thread per (b,t) position; Wout staged in LDS, broadcast float4 reads.
// ---------------------------------------------------------------------------
__global__ __launch_bounds__(256) void k_emis(
    const float* __restrict__ hout,   // [131072][100]
    const float* __restrict__ Wout,   // [11][100]
    const float* __restrict__ bout,   // [11]
    float* __restrict__ logits)       // [131072][11]
{
    __shared__ float Wl[1104];
    __shared__ float bl[11];
    const int tid = threadIdx.x;
    for (int i = tid; i < 1100; i += 256) Wl[i] = Wout[i];
    if (tid < 11) bl[tid] = bout[tid];
    __syncthreads();

    const size_t bt = (size_t)blockIdx.x * 256 + tid;
    const float4* h4 = (const float4*)(hout + bt * 100);
    float acc[11];
    #pragma unroll
    for (int k = 0; k < 11; ++k) acc[k] = bl[k];
    #pragma unroll
    for (int q = 0; q < 25; ++q) {
        float4 v = h4[q];
        #pragma unroll
        for (int k = 0; k < 11; ++k) {
            const float4 wv = *(const float4*)&Wl[k * 100 + q * 4];
            acc[k] = fmaf(v.x, wv.x, fmaf(v.y, wv.y, fmaf(v.z, wv.z, fmaf(v.w, wv.w, acc[k]))));
        }
    }
    #pragma unroll
    for (int k = 0; k < 11; ++k) logits[bt * 11 + k] = acc[k];
}

// ---------------------------------------------------------------------------
// Kernel 4: CRF forward scan + logsumexp score + fused Viterbi backtrace.
// One wave (64 threads) per batch element; lane==cur tag (11 active).
// Backpointers kept in LDS as u8 [512][12].
// Op ordering mirrors reference: smat = (alpha + frame) + trans; argmax is
// first-max (strict >) to match jnp.argmax ties.
// ---------------------------------------------------------------------------
__global__ __launch_bounds__(64) void k_crf(
    const float* __restrict__ logits,   // [131072][11]
    const int* __restrict__ mask,       // [256][512]
    const float* __restrict__ trans,    // [11][11]
    float* __restrict__ scores,         // [256]
    float* __restrict__ paths)          // [256][512] (as float)
{
    const int b = blockIdx.x;
    const int lane = threadIdx.x;

    __shared__ float tr[121];
    __shared__ float al[12];
    __shared__ unsigned char bp[512][12];

    for (int i = lane; i < 121; i += 64) tr[i] = trans[i];
    if (lane < 12) al[lane] = (lane == 9) ? 0.f : -1000.f;
    __syncthreads();

    const size_t lbase = (size_t)b * 512;

    for (int t = 0; t < 512; ++t) {
        const int mt = mask[lbase + t];
        float na = 0.f; int amax = 0;
        if (lane < 11) {
            const float f = logits[(lbase + t) * 11 + lane];
            float vmax = -1e30f;
            float v[11];
            #pragma unroll
            for (int p = 0; p < 11; ++p) {
                float vv = (al[p] + f) + tr[p * 11 + lane];
                v[p] = vv;
                if (vv > vmax) { vmax = vv; amax = p; }
            }
            float s = 0.f;
            #pragma unroll
            for (int p = 0; p < 11; ++p) s += expf(v[p] - vmax);
            na = vmax + logf(s);
        }
        __syncthreads();
        if (lane < 11) {
            if (mt > 0) {
                al[lane] = na;
                bp[t][lane] = (unsigned char)amax;
            } else {
                bp[t][lane] = (unsigned char)lane;
            }
        }
        __syncthreads();
    }

    // final scores + argmax (STOP = 10)
    float fin = (lane < 11) ? (al[lane] + tr[lane * 11 + 10]) : -1e30f;
    float m = fin;
    int am = (lane < 11) ? lane : 1000;
    #pragma unroll
    for (int off = 8; off >= 1; off >>= 1) {
        float om = __shfl_xor(m, off, 16);
        int   oa = __shfl_xor(am, off, 16);
        if (om > m || (om == m && oa < am)) { m = om; am = oa; }
    }
    float s = (lane < 11) ? expf(fin - m) : 0.f;
    #pragma unroll
    for (int off = 8; off >= 1; off >>= 1) s += __shfl_xor(s, off, 16);

    if (lane == 0) {
        scores[b] = m + logf(s);
        int cur = am;
        paths[lbase + 511] = (float)cur;
        for (int t = 511; t >= 1; --t) {
            cur = bp[t][cur];
            paths[lbase + t - 1] = (float)cur;
        }
    }
}

// ---------------------------------------------------------------------------
extern "C" void kernel_launch(void* const* d_in, const int* in_sizes, int n_in,
                              void* d_out, int out_size, void* d_ws, size_t ws_size,
                              hipStream_t stream) {
    const float* emb   = (const float*)d_in[0];
    const int*   imask = (const int*)d_in[1];
    const float* Wihf  = (const float*)d_in[2];
    const float* Whhf  = (const float*)d_in[3];
    const float* bf_   = (const float*)d_in[4];
    const float* Wihb  = (const float*)d_in[5];
    const float* Whhb  = (const float*)d_in[6];
    const float* bb_   = (const float*)d_in[7];
    const float* Wout  = (const float*)d_in[8];
    const float* bout  = (const float*)d_in[9];
    const float* trans = (const float*)d_in[10];

    float* out = (float*)d_out;
    float* ws  = (float*)d_ws;
    float* xw     = ws;                          // 131072*400 f32 = 209.7 MB
    float* hout   = xw + (size_t)131072 * 400;   // 131072*100 f32 = 52.4 MB
    float* logits = hout + (size_t)131072 * 100; // 131072*11  f32 = 5.8 MB

    k_gemm_xw<<<dim3(512, 7), 256, 0, stream>>>(emb, Wihf, Wihb, xw);
    k_lstm<<<512, 256, 0, stream>>>(xw, Whhf, Whhb, bf_, bb_, hout);
    k_emis<<<512, 256, 0, stream>>>(hout, Wout, bout, logits);
    k_crf<<<256, 64, 0, stream>>>(logits, imask, trans, out, out + 256);
}

// Round 2
// 1212.317 us; speedup vs baseline: 1.8367x; 1.8367x over previous
//
#include <hip/hip_runtime.h>
#include <math.h>

// Problem constants
// B=256, T=512, E=768, Hd=50, 4*Hd=200, H=100, K=11, START=9, STOP=10, NEG=-1000
// M = B*T = 131072

typedef _Float16 half8 __attribute__((ext_vector_type(8)));
typedef _Float16 half4 __attribute__((ext_vector_type(4)));
typedef float f32x4 __attribute__((ext_vector_type(4)));

// ---------------------------------------------------------------------------
// Kernel 1: xw[M][400] = emb[M][768] @ concat(W_ih_f, W_ih_b)^T
// Split-precision fp16 MFMA (hi+lo, 3 products) => ~fp32 accuracy at f16 rate.
// BM=128, BN=80 (5 n-blocks cover 400), BK=64, 256 thr, 4 waves of 32x80.
// LDS XOR-swizzle (slot ^= row&7) for conflict-free ds_read_b128.
// XCD-chunk swizzle: 5 n-blocks of one m-tile land on same XCD (A L2 reuse).
// ---------------------------------------------------------------------------
__global__ __launch_bounds__(256) void k_gemm_split(
    const float* __restrict__ emb,
    const float* __restrict__ Wf,     // [200][768]
    const float* __restrict__ Wb,     // [200][768]
    float* __restrict__ xw)           // [M][400]
{
    __shared__ _Float16 Ah[128 * 64];
    __shared__ _Float16 Al[128 * 64];
    __shared__ _Float16 Bh[80 * 64];
    __shared__ _Float16 Bl[80 * 64];

    // 5120 blocks total; chunk 640 per XCD; nb is the fast dim within a chunk
    const int bid = blockIdx.x;
    const int wg  = (bid & 7) * 640 + (bid >> 3);
    const int mt  = wg / 5;
    const int nb  = wg - mt * 5;
    const size_t m0 = (size_t)mt * 128;
    const int n0 = nb * 80;

    const int tid  = threadIdx.x;
    const int lane = tid & 63;
    const int w    = tid >> 6;        // wave 0..3, rows w*32..+31
    const int grp  = lane >> 4;       // 0..3
    const int r16  = lane & 15;

    f32x4 acc[2][5];
    #pragma unroll
    for (int m = 0; m < 2; ++m)
        #pragma unroll
        for (int n = 0; n < 5; ++n) acc[m][n] = (f32x4){0.f, 0.f, 0.f, 0.f};

    for (int kt = 0; kt < 12; ++kt) {
        const int k0 = kt * 64;
        __syncthreads();

        // ---- stage A: 128x64 f32 -> hi/lo fp16, swizzled ----
        #pragma unroll
        for (int j = 0; j < 8; ++j) {
            const int flat = j * 256 + tid;      // 0..2047 float4 slots
            const int row  = flat >> 4;          // 0..127
            const int q    = flat & 15;          // float4 col
            const float4 v = *(const float4*)(emb + (m0 + row) * 768 + k0 + q * 4);
            half4 hv, lv;
            hv[0] = (_Float16)v.x; lv[0] = (_Float16)(v.x - (float)hv[0]);
            hv[1] = (_Float16)v.y; lv[1] = (_Float16)(v.y - (float)hv[1]);
            hv[2] = (_Float16)v.z; lv[2] = (_Float16)(v.z - (float)hv[2]);
            hv[3] = (_Float16)v.w; lv[3] = (_Float16)(v.w - (float)hv[3]);
            const int s    = (q >> 1) ^ (row & 7);
            const int addr = row * 64 + s * 8 + (q & 1) * 4;
            *(half4*)(Ah + addr) = hv;
            *(half4*)(Al + addr) = lv;
        }
        // ---- stage B: 80x64 f32 (rows n0..n0+79 of concat W) ----
        #pragma unroll
        for (int j = 0; j < 5; ++j) {
            const int flat = j * 256 + tid;      // 0..1279
            const int row  = flat >> 4;          // 0..79
            const int q    = flat & 15;
            const int n    = n0 + row;
            const float* src = (n < 200) ? (Wf + (size_t)n * 768)
                                         : (Wb + (size_t)(n - 200) * 768);
            const float4 v = *(const float4*)(src + k0 + q * 4);
            half4 hv, lv;
            hv[0] = (_Float16)v.x; lv[0] = (_Float16)(v.x - (float)hv[0]);
            hv[1] = (_Float16)v.y; lv[1] = (_Float16)(v.y - (float)hv[1]);
            hv[2] = (_Float16)v.z; lv[2] = (_Float16)(v.z - (float)hv[2]);
            hv[3] = (_Float16)v.w; lv[3] = (_Float16)(v.w - (float)hv[3]);
            const int s    = (q >> 1) ^ (row & 7);
            const int addr = row * 64 + s * 8 + (q & 1) * 4;
            *(half4*)(Bh + addr) = hv;
            *(half4*)(Bl + addr) = lv;
        }
        __syncthreads();

        // ---- compute: 2 k-steps of 32 ----
        #pragma unroll
        for (int ks = 0; ks < 2; ++ks) {
            const int kslot = ks * 4 + grp;
            half8 ah[2], al[2], bh[5], bl[5];
            #pragma unroll
            for (int m = 0; m < 2; ++m) {
                const int row = w * 32 + m * 16 + r16;
                const int ad  = row * 64 + (kslot ^ (row & 7)) * 8;
                ah[m] = *(half8*)(Ah + ad);
                al[m] = *(half8*)(Al + ad);
            }
            #pragma unroll
            for (int n = 0; n < 5; ++n) {
                const int row = n * 16 + r16;
                const int ad  = row * 64 + (kslot ^ (row & 7)) * 8;
                bh[n] = *(half8*)(Bh + ad);
                bl[n] = *(half8*)(Bl + ad);
            }
            #pragma unroll
            for (int m = 0; m < 2; ++m)
                #pragma unroll
                for (int n = 0; n < 5; ++n) {
                    acc[m][n] = __builtin_amdgcn_mfma_f32_16x16x32_f16(ah[m], bh[n], acc[m][n], 0, 0, 0);
                    acc[m][n] = __builtin_amdgcn_mfma_f32_16x16x32_f16(ah[m], bl[n], acc[m][n], 0, 0, 0);
                    acc[m][n] = __builtin_amdgcn_mfma_f32_16x16x32_f16(al[m], bh[n], acc[m][n], 0, 0, 0);
                }
        }
    }

    // ---- epilogue: C/D layout col=lane&15, row=(lane>>4)*4+i ----
    #pragma unroll
    for (int m = 0; m < 2; ++m) {
        #pragma unroll
        for (int n = 0; n < 5; ++n) {
            #pragma unroll
            for (int i = 0; i < 4; ++i) {
                const size_t row = m0 + w * 32 + m * 16 + (lane >> 4) * 4 + i;
                const int    col = n0 + n * 16 + (lane & 15);
                xw[row * 400 + col] = acc[m][n][i];
            }
        }
    }
}

// ---------------------------------------------------------------------------
// Kernel 2: bidirectional LSTM recurrence. One block per (batch, dir).
// ---------------------------------------------------------------------------
__global__ __launch_bounds__(256) void k_lstm(
    const float* __restrict__ xw,     // [131072][400] (fwd gates 0..199, bwd 200..399)
    const float* __restrict__ Whh_f,  // [200][50]
    const float* __restrict__ Whh_b,
    const float* __restrict__ bf_,    // [200]
    const float* __restrict__ bb_,
    float* __restrict__ hout)         // [131072][100] (fwd 0..49, bwd 50..99)
{
    const int b   = blockIdx.x >> 1;
    const int dir = blockIdx.x & 1;
    const int g   = threadIdx.x;

    __shared__ float h_s[52];
    __shared__ float g_s[200];

    const float* Whh  = dir ? Whh_b : Whh_f;
    const float* bias = dir ? bb_ : bf_;

    float w[52];
    float bg = 0.f;
    if (g < 200) {
        #pragma unroll
        for (int j = 0; j < 50; ++j) w[j] = Whh[g * 50 + j];
        w[50] = 0.f; w[51] = 0.f;
        bg = bias[g];
    } else {
        #pragma unroll
        for (int j = 0; j < 52; ++j) w[j] = 0.f;
    }

    if (g < 52) h_s[g] = 0.f;
    float c = 0.f;
    __syncthreads();

    const size_t base = (size_t)b * 512;

    float xv = 0.f;
    {
        int t0 = dir ? 511 : 0;
        if (g < 200) xv = xw[(base + t0) * 400 + dir * 200 + g];
    }

    for (int it = 0; it < 512; ++it) {
        const int t = dir ? (511 - it) : it;
        float xcur = xv;
        if (it + 1 < 512) {
            int tn = dir ? (510 - it) : (it + 1);
            if (g < 200) xv = xw[(base + tn) * 400 + dir * 200 + g];
        }

        float sum = bg + xcur;
        const float4* h4 = (const float4*)h_s;
        #pragma unroll
        for (int q = 0; q < 13; ++q) {
            float4 hv = h4[q];
            sum = fmaf(w[q * 4 + 0], hv.x, sum);
            sum = fmaf(w[q * 4 + 1], hv.y, sum);
            sum = fmaf(w[q * 4 + 2], hv.z, sum);
            sum = fmaf(w[q * 4 + 3], hv.w, sum);
        }
        if (g < 200) g_s[g] = sum;
        __syncthreads();

        if (g < 50) {
            float gi = g_s[g];
            float gf = g_s[g + 50];
            float gg = g_s[g + 100];
            float go = g_s[g + 150];
            float si = 1.f / (1.f + expf(-gi));
            float sf = 1.f / (1.f + expf(-gf));
            float so = 1.f / (1.f + expf(-go));
            c = sf * c + si * tanhf(gg);
            float h = so * tanhf(c);
            hout[(base + t) * 100 + dir * 50 + g] = h;
            h_s[g] = h;
        }
        __syncthreads();
    }
}

// ---------------------------------------------------------------------------
// Kernel 3: emissions logits[bt][11] = hout[bt][100] @ Wout^T + bout
// ---------------------------------------------------------------------------
__global__ __launch_bounds__(256) void k_emis(
    const float* __restrict__ hout,   // [131072][100]
    const float* __restrict__ Wout,   // [11][100]
    const float* __restrict__ bout,   // [11]
    float* __restrict__ logits)       // [131072][11]
{
    __shared__ float Wl[1104];
    __shared__ float bl[11];
    const int tid = threadIdx.x;
    for (int i = tid; i < 1100; i += 256) Wl[i] = Wout[i];
    if (tid < 11) bl[tid] = bout[tid];
    __syncthreads();

    const size_t bt = (size_t)blockIdx.x * 256 + tid;
    const float4* h4 = (const float4*)(hout + bt * 100);
    float acc[11];
    #pragma unroll
    for (int k = 0; k < 11; ++k) acc[k] = bl[k];
    #pragma unroll
    for (int q = 0; q < 25; ++q) {
        float4 v = h4[q];
        #pragma unroll
        for (int k = 0; k < 11; ++k) {
            const float4 wv = *(const float4*)&Wl[k * 100 + q * 4];
            acc[k] = fmaf(v.x, wv.x, fmaf(v.y, wv.y, fmaf(v.z, wv.z, fmaf(v.w, wv.w, acc[k]))));
        }
    }
    #pragma unroll
    for (int k = 0; k < 11; ++k) logits[bt * 11 + k] = acc[k];
}

// ---------------------------------------------------------------------------
// Kernel 4: CRF forward scan + logsumexp score + fused Viterbi backtrace.
// ---------------------------------------------------------------------------
__global__ __launch_bounds__(64) void k_crf(
    const float* __restrict__ logits,   // [131072][11]
    const int* __restrict__ mask,       // [256][512]
    const float* __restrict__ trans,    // [11][11]
    float* __restrict__ scores,         // [256]
    float* __restrict__ paths)          // [256][512] (as float)
{
    const int b = blockIdx.x;
    const int lane = threadIdx.x;

    __shared__ float tr[121];
    __shared__ float al[12];
    __shared__ unsigned char bp[512][12];

    for (int i = lane; i < 121; i += 64) tr[i] = trans[i];
    if (lane < 12) al[lane] = (lane == 9) ? 0.f : -1000.f;
    __syncthreads();

    const size_t lbase = (size_t)b * 512;

    for (int t = 0; t < 512; ++t) {
        const int mt = mask[lbase + t];
        float na = 0.f; int amax = 0;
        if (lane < 11) {
            const float f = logits[(lbase + t) * 11 + lane];
            float vmax = -1e30f;
            float v[11];
            #pragma unroll
            for (int p = 0; p < 11; ++p) {
                float vv = (al[p] + f) + tr[p * 11 + lane];
                v[p] = vv;
                if (vv > vmax) { vmax = vv; amax = p; }
            }
            float s = 0.f;
            #pragma unroll
            for (int p = 0; p < 11; ++p) s += expf(v[p] - vmax);
            na = vmax + logf(s);
        }
        __syncthreads();
        if (lane < 11) {
            if (mt > 0) {
                al[lane] = na;
                bp[t][lane] = (unsigned char)amax;
            } else {
                bp[t][lane] = (unsigned char)lane;
            }
        }
        __syncthreads();
    }

    // final scores + argmax (STOP = 10)
    float fin = (lane < 11) ? (al[lane] + tr[lane * 11 + 10]) : -1e30f;
    float m = fin;
    int am = (lane < 11) ? lane : 1000;
    #pragma unroll
    for (int off = 8; off >= 1; off >>= 1) {
        float om = __shfl_xor(m, off, 16);
        int   oa = __shfl_xor(am, off, 16);
        if (om > m || (om == m && oa < am)) { m = om; am = oa; }
    }
    float s = (lane < 11) ? expf(fin - m) : 0.f;
    #pragma unroll
    for (int off = 8; off >= 1; off >>= 1) s += __shfl_xor(s, off, 16);

    if (lane == 0) {
        scores[b] = m + logf(s);
        int cur = am;
        paths[lbase + 511] = (float)cur;
        for (int t = 511; t >= 1; --t) {
            cur = bp[t][cur];
            paths[lbase + t - 1] = (float)cur;
        }
    }
}

// ---------------------------------------------------------------------------
extern "C" void kernel_launch(void* const* d_in, const int* in_sizes, int n_in,
                              void* d_out, int out_size, void* d_ws, size_t ws_size,
                              hipStream_t stream) {
    const float* emb   = (const float*)d_in[0];
    const int*   imask = (const int*)d_in[1];
    const float* Wihf  = (const float*)d_in[2];
    const float* Whhf  = (const float*)d_in[3];
    const float* bf_   = (const float*)d_in[4];
    const float* Wihb  = (const float*)d_in[5];
    const float* Whhb  = (const float*)d_in[6];
    const float* bb_   = (const float*)d_in[7];
    const float* Wout  = (const float*)d_in[8];
    const float* bout  = (const float*)d_in[9];
    const float* trans = (const float*)d_in[10];

    float* out = (float*)d_out;
    float* ws  = (float*)d_ws;
    float* xw     = ws;                          // 131072*400 f32 = 209.7 MB
    float* hout   = xw + (size_t)131072 * 400;   // 131072*100 f32 = 52.4 MB
    float* logits = hout + (size_t)131072 * 100; // 131072*11  f32 = 5.8 MB

    k_gemm_split<<<5120, 256, 0, stream>>>(emb, Wihf, Wihb, xw);
    k_lstm<<<512, 256, 0, stream>>>(xw, Whhf, Whhb, bf_, bb_, hout);
    k_emis<<<512, 256, 0, stream>>>(hout, Wout, bout, logits);
    k_crf<<<256, 64, 0, stream>>>(logits, imask, trans, out, out + 256);
}